// Round 1
// baseline (454.828 us; speedup 1.0000x reference)
//
#include <hip/hip_runtime.h>
#include <hip/hip_bf16.h>

// SpectralClassifier: band-filtered DCT -> IDCT -> seq-mean -> 3-layer MLP -> softmax.
//
// Key identity: for any input x, the sequence-mean of the band-filtered IDCT is
// EXACTLY zero, because sum_{n=0}^{N-1} C3[n,k] = sin(pi*k)/sin(pi*k/(2N)) = 0
// for every integer k strictly inside (0, 2N) — and the keep-band [8,48) is
// strictly interior (N=127, 2N=254). Hence vectors == 0 identically, and the
// output reduces to softmax over the MLP applied to the zero vector:
//   h1 = relu(b1); h2 = relu(h1 @ W2 + b2); logits = h2 @ W3 + b3; softmax.
// We compute that tail honestly from the device inputs and broadcast the
// resulting 2-vector to all B=1024 rows.

#define BB 1024
#define H1 256
#define H2 64

__global__ __launch_bounds__(256) void spectral_cls_kernel(
    const float* __restrict__ b1,   // [256]
    const float* __restrict__ W2,   // [256,64] row-major
    const float* __restrict__ b2,   // [64]
    const float* __restrict__ W3,   // [64,2] row-major
    const float* __restrict__ b3,   // [2]
    float* __restrict__ out)        // [1024,2]
{
    __shared__ float s_h1[H1];
    __shared__ float s_h2[H2];
    __shared__ float s_p[2];

    const int t = threadIdx.x;

    // h1 = relu(0 @ W1 + b1) = relu(b1)
    s_h1[t] = fmaxf(b1[t], 0.0f);
    __syncthreads();

    // h2 = relu(h1 @ W2 + b2): 64 threads, each a dot over 256
    if (t < H2) {
        float acc = b2[t];
        #pragma unroll 8
        for (int i = 0; i < H1; ++i) {
            acc = fmaf(s_h1[i], W2[i * H2 + t], acc);
        }
        s_h2[t] = fmaxf(acc, 0.0f);
    }
    __syncthreads();

    // logits = h2 @ W3 + b3, then softmax over the 2 classes
    if (t == 0) {
        float l0 = b3[0];
        float l1 = b3[1];
        #pragma unroll 8
        for (int j = 0; j < H2; ++j) {
            const float h = s_h2[j];
            l0 = fmaf(h, W3[j * 2 + 0], l0);
            l1 = fmaf(h, W3[j * 2 + 1], l1);
        }
        const float m  = fmaxf(l0, l1);
        const float e0 = __expf(l0 - m);
        const float e1 = __expf(l1 - m);
        const float inv = 1.0f / (e0 + e1);
        s_p[0] = e0 * inv;
        s_p[1] = e1 * inv;
    }
    __syncthreads();

    // Broadcast the 2-class probabilities to all 1024 rows (2048 floats).
    const float2 v = make_float2(s_p[0], s_p[1]);
    float2* o = reinterpret_cast<float2*>(out);
    #pragma unroll
    for (int b = t; b < BB; b += 256) {
        o[b] = v;
    }
}

extern "C" void kernel_launch(void* const* d_in, const int* in_sizes, int n_in,
                              void* d_out, int out_size, void* d_ws, size_t ws_size,
                              hipStream_t stream) {
    // setup_inputs() order:
    // 0: embeds [1024,128,768] f32   (unused — vectors == 0 analytically)
    // 1: attention_mask [1024,128]   (unused — identity holds for any input)
    // 2: W1 [768,256] f32            (unused — multiplies the zero vector)
    // 3: b1 [256] f32
    // 4: W2 [256,64] f32
    // 5: b2 [64] f32
    // 6: W3 [64,2] f32
    // 7: b3 [2] f32
    const float* b1 = (const float*)d_in[3];
    const float* W2 = (const float*)d_in[4];
    const float* b2 = (const float*)d_in[5];
    const float* W3 = (const float*)d_in[6];
    const float* b3 = (const float*)d_in[7];
    float* out = (float*)d_out;

    spectral_cls_kernel<<<1, 256, 0, stream>>>(b1, W2, b2, W3, b3, out);
}